// Round 3
// baseline (30.824 us; speedup 1.0000x reference)
//
#include <hip/hip_runtime.h>
#include <math.h>

#define N_ROWS 4096
#define D_DIM  128
#define K_CLS  512
#define TN     8
#define EPS    1e-6f

// One block = TN=8 rows x all 512 classes. 512 threads (8 waves); thread owns k = tid.
// dist^2(r,k) = sxs[r] - 2*(acc[r] + eps*aw1) + aw2
//   sxs[r] = sum_d (x[r][d]+eps)^2 ; acc[r] = sum_d x[r][d]*w[d][k]
//   aw1 = sum_d w[d][k] ; aw2 = sum_d w[d][k]^2
__global__ __launch_bounds__(512) void proto_fused_kernel(
    const float* __restrict__ x,      // (N, D)
    const int*   __restrict__ label,  // (N,)
    const float* __restrict__ w,      // (D, K)
    float* __restrict__ scores,       // (N, K)
    float* __restrict__ row_loss)     // (N,)
{
    const int tid  = threadIdx.x;
    const int wave = tid >> 6;
    const int lane = tid & 63;
    const int n0   = blockIdx.x * TN;

    __shared__ float xs_t[D_DIM][TN];   // 4 KB : x tile transposed [d][row]
    __shared__ float sxs[TN];           // per-row sum (x+eps)^2
    __shared__ float wredm[8][TN];      // cross-wave max partials
    __shared__ float wrede[8][TN];      // cross-wave sum partials

    // ---- stage: wave w owns row w; lane covers d = 2*lane, 2*lane+1 ----
    {
        const float2 xv = *(const float2*)&x[(size_t)(n0 + wave) * D_DIM + lane * 2];
        xs_t[lane * 2 + 0][wave] = xv.x;
        xs_t[lane * 2 + 1][wave] = xv.y;
        float p = 0.f;
        const float e0 = xv.x + EPS;
        const float e1 = xv.y + EPS;
        p = fmaf(e0, e0, p);
        p = fmaf(e1, e1, p);
#pragma unroll
        for (int off = 32; off >= 1; off >>= 1) p += __shfl_xor(p, off);
        if (lane == 0) sxs[wave] = p;
    }
    __syncthreads();

    // ---- main loop ----
    float acc[TN];
#pragma unroll
    for (int r = 0; r < TN; ++r) acc[r] = 0.f;
    float aw1 = 0.f, aw2 = 0.f;

#pragma unroll 8
    for (int d = 0; d < D_DIM; ++d) {
        const float wv = w[d * K_CLS + tid];
        aw1 += wv;
        aw2 = fmaf(wv, wv, aw2);
        const float4 xa = *(const float4*)&xs_t[d][0];
        const float4 xb = *(const float4*)&xs_t[d][4];
        acc[0] = fmaf(xa.x, wv, acc[0]);
        acc[1] = fmaf(xa.y, wv, acc[1]);
        acc[2] = fmaf(xa.z, wv, acc[2]);
        acc[3] = fmaf(xa.w, wv, acc[3]);
        acc[4] = fmaf(xb.x, wv, acc[4]);
        acc[5] = fmaf(xb.y, wv, acc[5]);
        acc[6] = fmaf(xb.z, wv, acc[6]);
        acc[7] = fmaf(xb.w, wv, acc[7]);
    }

    // ---- scores (registers) + global write ----
    float s[TN];
#pragma unroll
    for (int r = 0; r < TN; ++r) {
        const float dist = sxs[r] - 2.f * fmaf(EPS, aw1, acc[r]) + aw2;
        s[r] = -sqrtf(dist);
        scores[(size_t)(n0 + r) * K_CLS + tid] = s[r];
    }

    // ---- row max: wave shuffle reduce, then cross-wave via LDS ----
#pragma unroll
    for (int r = 0; r < TN; ++r) {
        float t = s[r];
#pragma unroll
        for (int off = 32; off >= 1; off >>= 1) t = fmaxf(t, __shfl_xor(t, off));
        if (lane == 0) wredm[wave][r] = t;
    }
    __syncthreads();

    float m[TN];
#pragma unroll
    for (int r = 0; r < TN; ++r) {
        float t = wredm[0][r];
#pragma unroll
        for (int ww = 1; ww < 8; ++ww) t = fmaxf(t, wredm[ww][r]);
        m[r] = t;
    }

    // ---- row sum of exp(s - m) ----
#pragma unroll
    for (int r = 0; r < TN; ++r) {
        float e = expf(s[r] - m[r]);
#pragma unroll
        for (int off = 32; off >= 1; off >>= 1) e += __shfl_xor(e, off);
        if (lane == 0) wrede[wave][r] = e;
    }
    __syncthreads();

#pragma unroll
    for (int r = 0; r < TN; ++r) {
        float esum = wrede[0][r];
#pragma unroll
        for (int ww = 1; ww < 8; ++ww) esum += wrede[ww][r];
        const int lab = label[n0 + r];   // block-uniform -> scalar load
        if (tid == lab)
            row_loss[n0 + r] = -(s[r] - m[r] - logf(esum));
    }
}

// Deterministic single-block reduction of per-row losses -> mean.
__global__ __launch_bounds__(256) void loss_reduce_kernel(
    const float* __restrict__ row_loss, float* __restrict__ out)
{
    __shared__ float red[4];
    const int tid = threadIdx.x;
    float sum = 0.f;
    for (int i = tid; i < N_ROWS; i += 256) sum += row_loss[i];
#pragma unroll
    for (int off = 32; off >= 1; off >>= 1) sum += __shfl_xor(sum, off);
    if ((tid & 63) == 0) red[tid >> 6] = sum;
    __syncthreads();
    if (tid == 0)
        out[0] = (red[0] + red[1] + red[2] + red[3]) * (1.0f / N_ROWS);
}

extern "C" void kernel_launch(void* const* d_in, const int* in_sizes, int n_in,
                              void* d_out, int out_size, void* d_ws, size_t ws_size,
                              hipStream_t stream)
{
    const float* x     = (const float*)d_in[0];
    const int*   label = (const int*)d_in[1];
    const float* w     = (const float*)d_in[2];

    float* scores   = (float*)d_out;                           // N*K floats
    float* loss_out = (float*)d_out + (size_t)N_ROWS * K_CLS;  // 1 float
    float* row_loss = (float*)d_ws;                            // N floats scratch

    proto_fused_kernel<<<N_ROWS / TN, 512, 0, stream>>>(x, label, w, scores, row_loss);
    loss_reduce_kernel<<<1, 256, 0, stream>>>(row_loss, loss_out);
}

// Round 4
// 24.205 us; speedup vs baseline: 1.2734x; 1.2734x over previous
//
#include <hip/hip_runtime.h>
#include <math.h>

#define N_ROWS 4096
#define D_DIM  128
#define K_CLS  512
#define EPS    1e-6f

typedef __attribute__((ext_vector_type(8))) short short8v;
typedef __attribute__((ext_vector_type(4))) float f32x4;

__device__ __forceinline__ unsigned short f2bf(float f) {
    unsigned int u = __float_as_uint(f);
    u += 0x7FFF + ((u >> 16) & 1);   // round-to-nearest-even
    return (unsigned short)(u >> 16);
}

// ---- prep: pack W (D,K) f32 -> bf16 B-fragments + c[k] = sum w^2 - 2*eps*sum w ----
// B-fragment layout for mfma_f32_16x16x32_bf16: lane l holds col (l&15),
// k = (l>>4)*8 + j. Packed as bpk[((t*32 + c)*64 + lane)*8 + j],
// t = k-step (d = 32t..32t+31), c = col-tile (cols 16c..16c+15).
__global__ __launch_bounds__(256) void prep_kernel(
    const float* __restrict__ w,
    unsigned short* __restrict__ bpk,   // 4*32*64*8 bf16
    float* __restrict__ c_arr)          // (K)
{
    const int b   = blockIdx.x;
    const int tid = threadIdx.x;
    if (b < 32) {
        const int gtid = b * 256 + tid;      // 0..8191
        const int lane = gtid & 63;
        const int c    = (gtid >> 6) & 31;
        const int t    = gtid >> 11;         // 0..3
        const int col  = c * 16 + (lane & 15);
        const int d0   = t * 32 + ((lane >> 4) << 3);
        unsigned short v[8];
#pragma unroll
        for (int j = 0; j < 8; ++j)
            v[j] = f2bf(w[(d0 + j) * K_CLS + col]);
        uint4 out;
        out.x = v[0] | ((unsigned)v[1] << 16);
        out.y = v[2] | ((unsigned)v[3] << 16);
        out.z = v[4] | ((unsigned)v[5] << 16);
        out.w = v[6] | ((unsigned)v[7] << 16);
        *(uint4*)&bpk[(size_t)gtid * 8] = out;
    } else {
        const int k = (b - 32) * 256 + tid;  // 0..511
        float s1 = 0.f, s2 = 0.f;
#pragma unroll 8
        for (int d = 0; d < D_DIM; ++d) {
            const float v = w[d * K_CLS + k];
            s1 += v;
            s2 = fmaf(v, v, s2);
        }
        c_arr[k] = s2 - 2.f * EPS * s1;
    }
}

// ---- main: block = 16 rows x 512 cols, 512 threads (8 waves). ----
// wave w: cols 64w..64w+63 (4 col-tiles), 16 MFMAs. Fused softmax + loss.
__global__ __launch_bounds__(512) void proto_mfma_kernel(
    const float* __restrict__ x,
    const int*   __restrict__ label,
    const unsigned short* __restrict__ bpk,
    const float* __restrict__ c_arr,
    float* __restrict__ scores,
    float* __restrict__ row_loss)
{
    const int tid  = threadIdx.x;
    const int wave = tid >> 6;
    const int lane = tid & 63;
    const int n0   = blockIdx.x * 16;

    __shared__ float sc[16][K_CLS + 4];   // +4 pad: kills write bank conflicts
    __shared__ float sxs[16];

    // ---- sx[row] = sum_d (x+eps)^2 : threads 0..255, 16 chunks/row ----
    if (tid < 256) {
        const int row   = tid >> 4;
        const int chunk = tid & 15;
        const float4 a = *(const float4*)&x[(size_t)(n0 + row) * D_DIM + chunk * 8];
        const float4 b = *(const float4*)&x[(size_t)(n0 + row) * D_DIM + chunk * 8 + 4];
        float p = 0.f;
        p = fmaf(a.x + EPS, a.x + EPS, p);
        p = fmaf(a.y + EPS, a.y + EPS, p);
        p = fmaf(a.z + EPS, a.z + EPS, p);
        p = fmaf(a.w + EPS, a.w + EPS, p);
        p = fmaf(b.x + EPS, b.x + EPS, p);
        p = fmaf(b.y + EPS, b.y + EPS, p);
        p = fmaf(b.z + EPS, b.z + EPS, p);
        p = fmaf(b.w + EPS, b.w + EPS, p);
        p += __shfl_xor(p, 1);
        p += __shfl_xor(p, 2);
        p += __shfl_xor(p, 4);
        p += __shfl_xor(p, 8);
        if (chunk == 0) sxs[row] = p;
    }

    // ---- A fragments (identical for all waves; x tile is L1-hot) ----
    // lane l: row (l&15), k = (l>>4)*8 + j
    short8v afrag[4];
#pragma unroll
    for (int t = 0; t < 4; ++t) {
        const int row = n0 + (lane & 15);
        const int d0  = t * 32 + ((lane >> 4) << 3);
        const float4 a = *(const float4*)&x[(size_t)row * D_DIM + d0];
        const float4 b = *(const float4*)&x[(size_t)row * D_DIM + d0 + 4];
        short8v f;
        f[0] = (short)f2bf(a.x); f[1] = (short)f2bf(a.y);
        f[2] = (short)f2bf(a.z); f[3] = (short)f2bf(a.w);
        f[4] = (short)f2bf(b.x); f[5] = (short)f2bf(b.y);
        f[6] = (short)f2bf(b.z); f[7] = (short)f2bf(b.w);
        afrag[t] = f;
    }

    // ---- MFMA: acc[c] = X_tile * W[:, coltile] ----
    f32x4 acc[4];
#pragma unroll
    for (int c = 0; c < 4; ++c) acc[c] = (f32x4){0.f, 0.f, 0.f, 0.f};

#pragma unroll
    for (int c = 0; c < 4; ++c) {
        const int ctile = wave * 4 + c;
#pragma unroll
        for (int t = 0; t < 4; ++t) {
            const short8v bfrag =
                *(const short8v*)&bpk[(((size_t)t * 32 + ctile) * 64 + lane) * 8];
            acc[c] = __builtin_amdgcn_mfma_f32_16x16x32_bf16(afrag[t], bfrag, acc[c], 0, 0, 0);
        }
    }

    __syncthreads();   // sxs ready

    // ---- epilogue: score = -sqrt(sx[row] + c[col] - 2*dot) into LDS ----
    // C/D layout: col = lane&15, row = (lane>>4)*4 + reg
#pragma unroll
    for (int c = 0; c < 4; ++c) {
        const int col = (wave * 4 + c) * 16 + (lane & 15);
        const float ck = c_arr[col];
#pragma unroll
        for (int j = 0; j < 4; ++j) {
            const int row = (lane >> 4) * 4 + j;
            const float dist = sxs[row] + ck - 2.f * acc[c][j];
            sc[row][col] = -sqrtf(dist);
        }
    }
    __syncthreads();

    // ---- coalesced global write of the score tile ----
    {
        const int row = tid >> 5;
        const int r5  = tid & 31;
#pragma unroll
        for (int i = 0; i < 4; ++i) {
            const int colf = (i * 32 + r5) * 4;
            *(float4*)&scores[(size_t)(n0 + row) * K_CLS + colf] =
                *(const float4*)&sc[row][colf];
        }
    }

    // ---- softmax + loss: wave handles rows wave, wave+8 ----
#pragma unroll
    for (int rr = 0; rr < 2; ++rr) {
        const int r = wave + rr * 8;
        float v[8];
#pragma unroll
        for (int i = 0; i < 8; ++i) v[i] = sc[r][lane + 64 * i];
        float m = v[0];
#pragma unroll
        for (int i = 1; i < 8; ++i) m = fmaxf(m, v[i]);
#pragma unroll
        for (int off = 32; off >= 1; off >>= 1) m = fmaxf(m, __shfl_xor(m, off));
        float e = 0.f;
#pragma unroll
        for (int i = 0; i < 8; ++i) e += expf(v[i] - m);
#pragma unroll
        for (int off = 32; off >= 1; off >>= 1) e += __shfl_xor(e, off);
        if (lane == 0) {
            const int lab = label[n0 + r];
            row_loss[n0 + r] = -(sc[r][lab] - m - logf(e));
        }
    }
}

// Deterministic single-block reduction of per-row losses -> mean.
__global__ __launch_bounds__(256) void loss_reduce_kernel(
    const float* __restrict__ row_loss, float* __restrict__ out)
{
    __shared__ float red[4];
    const int tid = threadIdx.x;
    float sum = 0.f;
    for (int i = tid; i < N_ROWS; i += 256) sum += row_loss[i];
#pragma unroll
    for (int off = 32; off >= 1; off >>= 1) sum += __shfl_xor(sum, off);
    if ((tid & 63) == 0) red[tid >> 6] = sum;
    __syncthreads();
    if (tid == 0)
        out[0] = (red[0] + red[1] + red[2] + red[3]) * (1.0f / N_ROWS);
}

extern "C" void kernel_launch(void* const* d_in, const int* in_sizes, int n_in,
                              void* d_out, int out_size, void* d_ws, size_t ws_size,
                              hipStream_t stream)
{
    const float* x     = (const float*)d_in[0];
    const int*   label = (const int*)d_in[1];
    const float* w     = (const float*)d_in[2];

    float* scores   = (float*)d_out;                           // N*K floats
    float* loss_out = (float*)d_out + (size_t)N_ROWS * K_CLS;  // 1 float

    unsigned short* bpk = (unsigned short*)d_ws;               // 65536 bf16 = 128 KB
    float* c_arr    = (float*)((char*)d_ws + 131072);          // 512 floats
    float* row_loss = c_arr + K_CLS;                           // 4096 floats

    prep_kernel<<<34, 256, 0, stream>>>(w, bpk, c_arr);
    proto_mfma_kernel<<<N_ROWS / 16, 512, 0, stream>>>(x, label, bpk, c_arr,
                                                       scores, row_loss);
    loss_reduce_kernel<<<1, 256, 0, stream>>>(row_loss, loss_out);
}